// Round 8
// baseline (664.486 us; speedup 1.0000x reference)
//
#include <hip/hip_runtime.h>
#include <hip/hip_fp16.h>
#include <math.h>

#define M_TRAIN 100000
#define NQ 2048
#define DIM 128
#define KNN 16
#define NCLS 10

// Subsample for tau: every 16th train point; padded to 6272 = 49 * 128.
#define S_STRIDE 16
#define S_CNT (M_TRAIN / S_STRIDE)     // 6250
#define S_PAD 6272
#define SCH 49
#define SPC 128
#define TT 64
#define MQ 128
#define QSTR 136                       // LDS row stride in shorts (128 + 8 pad)

// Streaming bf16 filter (two halves of the train set)
#define CAP 768
#define TBH 50176                      // rows per half (49 * 1024)
#define FCH 49                         // chunks per half
#define FTC 1024                       // train rows per chunk
#define FNT 16                         // tiles per chunk (FTC/TT)
#define MARGIN 3.0f                    // proven in rounds 4-5

using bfrag = __attribute__((ext_vector_type(8))) short;
using cfrag = __attribute__((ext_vector_type(4))) float;

__device__ __forceinline__ bool better(float d1, int i1, float d2, int i2) {
    return (d1 < d2) || (d1 == d2 && i1 < i2);
}

__device__ __forceinline__ unsigned pack_bf16(float a, float b) {
    unsigned ua = __float_as_uint(a), ub = __float_as_uint(b);
    ua += 0x7fffu + ((ua >> 16) & 1u);   // RNE
    ub += 0x7fffu + ((ub >> 16) & 1u);
    return (ua >> 16) | (ub & 0xffff0000u);
}

__device__ __forceinline__ bfrag pack_bf16x8(const float* p) {
    union { unsigned u[4]; bfrag f; } r;
    r.u[0] = pack_bf16(p[0], p[1]);
    r.u[1] = pack_bf16(p[2], p[3]);
    r.u[2] = pack_bf16(p[4], p[5]);
    r.u[3] = pack_bf16(p[6], p[7]);
    return r.f;
}

// ---------------------------------------------------------------------------
// Kernel 0: squared norms, one wave per row.
__global__ void knn_norms(const float* __restrict__ train,
                          const float* __restrict__ x,
                          float* __restrict__ t2, float* __restrict__ x2) {
    int gw = (blockIdx.x * blockDim.x + threadIdx.x) >> 6;
    int lane = threadIdx.x & 63;
    if (gw >= M_TRAIN + NQ) return;
    const float* r = (gw < M_TRAIN) ? (train + (size_t)gw * DIM)
                                    : (x + (size_t)(gw - M_TRAIN) * DIM);
    float a = r[lane];
    float b = r[lane + 64];
    float s = a * a + b * b;
    #pragma unroll
    for (int off = 32; off > 0; off >>= 1)
        s += __shfl_down(s, off, 64);
    if (lane == 0) {
        if (gw < M_TRAIN) t2[gw] = s; else x2[gw - M_TRAIN] = s;
    }
}

__global__ void knn_zero_cnt(int* __restrict__ cnt) {
    int i = blockIdx.x * blockDim.x + threadIdx.x;
    if (i < NQ) cnt[i] = 0;
}

// ---------------------------------------------------------------------------
// Kernel 1: MFMA (bf16) approx-d2 over the stride-16 subsample -> fp16 matrix.
__global__ __launch_bounds__(256, 2)
void knn_sub_mfma(const float* __restrict__ x, const float* __restrict__ train,
                  const float* __restrict__ t2, const float* __restrict__ x2,
                  __half* __restrict__ dsub) {
    __shared__ short Q[MQ * QSTR];
    __shared__ short T[TT * QSTR];
    __shared__ float t2h[TT];
    int tid = threadIdx.x;
    int w = tid >> 6, lane = tid & 63;
    int rquad = lane >> 4, rcol = lane & 15;
    int qBase = blockIdx.y * MQ;
    int cBase = blockIdx.x * SPC;

    #pragma unroll
    for (int it = 0; it < 16; ++it) {
        int f = it * 256 + tid;
        int row = f >> 5, c4 = f & 31;
        float4 v = ((const float4*)x)[(size_t)(qBase + row) * (DIM / 4) + c4];
        uint2 p; p.x = pack_bf16(v.x, v.y); p.y = pack_bf16(v.z, v.w);
        *(uint2*)&Q[row * QSTR + c4 * 4] = p;
    }
    __syncthreads();

    float x2r[2][4];
    #pragma unroll
    for (int rt = 0; rt < 2; ++rt)
        #pragma unroll
        for (int reg = 0; reg < 4; ++reg)
            x2r[rt][reg] = x2[qBase + w * 32 + rt * 16 + rquad * 4 + reg];

    bfrag A[2][4];
    #pragma unroll
    for (int rt = 0; rt < 2; ++rt)
        #pragma unroll
        for (int ks = 0; ks < 4; ++ks) {
            int r = w * 32 + rt * 16 + rcol;
            A[rt][ks] = *(const bfrag*)&Q[r * QSTR + ks * 32 + rquad * 8];
        }

    const cfrag zero4 = {0.f, 0.f, 0.f, 0.f};
    for (int t = 0; t < 2; ++t) {
        __syncthreads();
        int sBase = cBase + t * TT;
        #pragma unroll
        for (int it = 0; it < 8; ++it) {
            int f = it * 256 + tid;
            int row = f >> 5, c4 = f & 31;
            int sj = sBase + row;
            bool ok = sj < S_CNT;
            float4 v = ok ? ((const float4*)train)[(size_t)sj * S_STRIDE * (DIM / 4) + c4]
                          : make_float4(0.f, 0.f, 0.f, 0.f);
            uint2 p; p.x = pack_bf16(v.x, v.y); p.y = pack_bf16(v.z, v.w);
            *(uint2*)&T[row * QSTR + c4 * 4] = p;
        }
        if (tid < TT) {
            int sj = sBase + tid;
            t2h[tid] = (sj < S_CNT) ? t2[(size_t)sj * S_STRIDE] : 1e30f;
        }
        __syncthreads();

        cfrag acc[2][4];
        #pragma unroll
        for (int ks = 0; ks < 4; ++ks) {
            bfrag B[4];
            #pragma unroll
            for (int ct = 0; ct < 4; ++ct) {
                int n = ct * 16 + rcol;
                B[ct] = *(const bfrag*)&T[n * QSTR + ks * 32 + rquad * 8];
            }
            #pragma unroll
            for (int rt = 0; rt < 2; ++rt)
                #pragma unroll
                for (int ct = 0; ct < 4; ++ct)
                    acc[rt][ct] = (ks == 0)
                        ? __builtin_amdgcn_mfma_f32_16x16x32_bf16(A[rt][0], B[ct], zero4, 0, 0, 0)
                        : __builtin_amdgcn_mfma_f32_16x16x32_bf16(A[rt][ks], B[ct], acc[rt][ct], 0, 0, 0);
        }

        float th[4];
        #pragma unroll
        for (int ct = 0; ct < 4; ++ct) th[ct] = t2h[ct * 16 + rcol];
        #pragma unroll
        for (int rt = 0; rt < 2; ++rt)
            #pragma unroll
            for (int ct = 0; ct < 4; ++ct)
                #pragma unroll
                for (int reg = 0; reg < 4; ++reg) {
                    float d2 = x2r[rt][reg] + th[ct] - 2.f * acc[rt][ct][reg];
                    int qrow = qBase + w * 32 + rt * 16 + rquad * 4 + reg;
                    int col = sBase + ct * 16 + rcol;
                    dsub[(size_t)qrow * S_PAD + col] = __float2half_rn(d2);
                }
    }
}

// ---------------------------------------------------------------------------
// Kernel 2: tau[q] = 16th-smallest value of dsub row q (values only).
__global__ __launch_bounds__(256)
void knn_select(const __half* __restrict__ dsub, float* __restrict__ tau) {
    __shared__ float wv[4];
    __shared__ int   wc[4];
    __shared__ float sv;
    __shared__ int   sc;
    int q = blockIdx.x, tid = threadIdx.x;
    int w = tid >> 6, lane = tid & 63;

    float bd[KNN];
    #pragma unroll
    for (int j = 0; j < KNN; ++j) bd[j] = 3.4e38f;
    for (int k = 0; k < 25; ++k) {
        int idx = k * 256 + tid;
        if (idx < S_PAD) {
            float v = __half2float(dsub[(size_t)q * S_PAD + idx]);
            if (v < bd[KNN - 1]) {
                bd[KNN - 1] = v;
                #pragma unroll
                for (int j = KNN - 1; j >= 1; --j)
                    if (bd[j] < bd[j - 1]) { float t = bd[j]; bd[j] = bd[j - 1]; bd[j - 1] = t; }
            }
        }
    }

    float last = 3.4e38f;
    for (int sel = 0; sel < KNN; ++sel) {
        float mv = bd[0]; int mj = 0;
        #pragma unroll
        for (int j = 1; j < KNN; ++j) if (bd[j] < mv) { mv = bd[j]; mj = j; }
        int mc = (tid << 4) | mj;
        #pragma unroll
        for (int off = 32; off > 0; off >>= 1) {
            float ov = __shfl_down(mv, off, 64);
            int   oc = __shfl_down(mc, off, 64);
            if (ov < mv) { mv = ov; mc = oc; }
        }
        if (lane == 0) { wv[w] = mv; wc[w] = mc; }
        __syncthreads();
        if (tid == 0) {
            float bv = wv[0]; int bc = wc[0];
            #pragma unroll
            for (int i = 1; i < 4; ++i) if (wv[i] < bv) { bv = wv[i]; bc = wc[i]; }
            sv = bv; sc = bc;
        }
        __syncthreads();
        last = sv;
        if (tid == (sc >> 4)) {
            int j0 = sc & 15;
            #pragma unroll
            for (int j = 0; j < KNN; ++j) if (j == j0) bd[j] = 3.4e38f;
        }
        __syncthreads();
    }
    if (tid == 0) tau[q] = last;
}

// ---------------------------------------------------------------------------
// Kernel 3: fp32 -> bf16 conversion of one train half (pad rows zero-filled).
// Runs AFTER knn_select: tb aliases the dead dsub region.
__global__ __launch_bounds__(256)
void knn_convert_bf16(const float* __restrict__ train,
                      unsigned int* __restrict__ tb, int rowBase) {
    int i = blockIdx.x * 256 + threadIdx.x;        // one thread per 4 floats
    int row = i >> 5, seg = i & 31;                // row in [0, TBH)
    int g = rowBase + row;
    float4 v = (g < M_TRAIN)
        ? ((const float4*)train)[(size_t)g * (DIM / 4) + seg]
        : make_float4(0.f, 0.f, 0.f, 0.f);
    uint2 p; p.x = pack_bf16(v.x, v.y); p.y = pack_bf16(v.z, v.w);
    ((uint2*)tb)[(size_t)row * 32 + seg] = p;
}

// ---------------------------------------------------------------------------
// Kernel 4: streaming bf16 MFMA filter over one train half. NO LDS, NO
// barriers. A-frags packed in-kernel from fp32 x (identical values to the
// round-5 LDS path); B-frags stream straight from bf16 tb (L2-resident,
// 256 KB per chunk, chunk-major block order).
// Pass condition: s >= 0.5*(x2[q]-tau[q]-MARGIN) + 0.5*t2[n].
__global__ __launch_bounds__(256, 2)
void knn_bf16_filter(const float* __restrict__ x, const short* __restrict__ tbb,
                     const float* __restrict__ t2, const float* __restrict__ x2,
                     const float* __restrict__ tau, int pBase0,
                     int* __restrict__ buf_i, int* __restrict__ cnt) {
    int tid = threadIdx.x;
    int w = tid >> 6, lane = tid & 63;
    int rquad = lane >> 4, rcol = lane & 15;
    int bid = blockIdx.x;                 // chunk-major: 16 q-blocks contiguous
    int chunk = bid >> 4, qb = bid & 15;
    int qBase = qb * MQ;
    int pLoc = chunk * FTC;               // local row within this half

    // A-frags: A[m=lane&15][k=(lane>>4)*8+j], packed fp32->bf16 in-kernel.
    bfrag A[2][4];
    float RC[2][4];
    #pragma unroll
    for (int rt = 0; rt < 2; ++rt) {
        int qrow = qBase + w * 32 + rt * 16 + rcol;
        #pragma unroll
        for (int ks = 0; ks < 4; ++ks)
            A[rt][ks] = pack_bf16x8(&x[(size_t)qrow * DIM + ks * 32 + rquad * 8]);
        #pragma unroll
        for (int reg = 0; reg < 4; ++reg) {
            int q = qBase + w * 32 + rt * 16 + rquad * 4 + reg;
            RC[rt][reg] = 0.5f * (x2[q] - tau[q] - MARGIN);
        }
    }

    const cfrag zero4 = {0.f, 0.f, 0.f, 0.f};
    for (int t = 0; t < FNT; ++t) {
        int tLoc = pLoc + t * TT;

        // 16 B-frags (B[n=rcol][k=rquad*8+j]) + per-column 0.5*t2.
        bfrag B[4][4];
        float th[4];
        #pragma unroll
        for (int ct = 0; ct < 4; ++ct) {
            int n = tLoc + ct * 16 + rcol;
            #pragma unroll
            for (int ks = 0; ks < 4; ++ks)
                B[ks][ct] = *(const bfrag*)&tbb[(size_t)n * DIM + ks * 32 + rquad * 8];
            int g = pBase0 + n;           // < 100352 = t2 allocation; pad rows
            th[ct] = 0.5f * t2[g];        // read poison harmlessly (idx guard)
        }

        cfrag acc[2][4];
        #pragma unroll
        for (int ks = 0; ks < 4; ++ks)
            #pragma unroll
            for (int rt = 0; rt < 2; ++rt)
                #pragma unroll
                for (int ct = 0; ct < 4; ++ct)
                    acc[rt][ct] = (ks == 0)
                        ? __builtin_amdgcn_mfma_f32_16x16x32_bf16(A[rt][0], B[0][ct], zero4, 0, 0, 0)
                        : __builtin_amdgcn_mfma_f32_16x16x32_bf16(A[rt][ks], B[ks][ct], acc[rt][ct], 0, 0, 0);

        #pragma unroll
        for (int rt = 0; rt < 2; ++rt)
            #pragma unroll
            for (int ct = 0; ct < 4; ++ct)
                #pragma unroll
                for (int reg = 0; reg < 4; ++reg) {
                    float s = acc[rt][ct][reg];
                    int idx = pBase0 + tLoc + ct * 16 + rcol;
                    if (s >= RC[rt][reg] + th[ct] && idx < M_TRAIN) {
                        int q = qBase + w * 32 + rt * 16 + rquad * 4 + reg;
                        int slot = atomicAdd(&cnt[q], 1);
                        if (slot < CAP)
                            buf_i[(size_t)q * CAP + slot] = idx;
                    }
                }
    }
}

// ---------------------------------------------------------------------------
// Kernel 5: exact fp32 re-rank + weighted vote. 256 thr: 16 lanes/candidate.
__global__ __launch_bounds__(256)
void knn_final(const float* __restrict__ x,
               const float* __restrict__ train,
               const float* __restrict__ t2v,
               const float* __restrict__ x2v,
               const int* __restrict__ buf_i,
               const int* __restrict__ cnt,
               const int* __restrict__ labels,
               float* __restrict__ out) {
    __shared__ float sd[CAP];
    __shared__ int   si[CAP];
    __shared__ float spr[NCLS];
    int q = blockIdx.x;
    int tid = threadIdx.x;
    int w = tid >> 6, lane = tid & 63;
    int grp = lane >> 4;
    int sub = lane & 15;
    int n = cnt[q]; if (n > CAP) n = CAP;

    const float4* xq = (const float4*)&x[(size_t)q * DIM + sub * 8];
    float4 qa = xq[0], qb = xq[1];
    float x2l = x2v[q];

    for (int base = 0; base < n; base += 16) {
        int i = base + w * 4 + grp;
        if (i < n) {
            int idx = buf_i[(size_t)q * CAP + i];
            const float4* tr = (const float4*)&train[(size_t)idx * DIM + sub * 8];
            float4 ta = tr[0], tb4 = tr[1];
            float s = qa.x * ta.x + qa.y * ta.y + qa.z * ta.z + qa.w * ta.w
                    + qb.x * tb4.x + qb.y * tb4.y + qb.z * tb4.z + qb.w * tb4.w;
            s += __shfl_xor(s, 1, 64);
            s += __shfl_xor(s, 2, 64);
            s += __shfl_xor(s, 4, 64);
            s += __shfl_xor(s, 8, 64);
            if (sub == 0) { sd[i] = x2l + t2v[idx] - 2.f * s; si[i] = idx; }
        }
    }
    __syncthreads();

    float kd[KNN];
    int   ki[KNN];
    for (int sel = 0; sel < KNN; ++sel) {
        if (w == 0) {
            float md = 3.4e38f; int mi = 0x7fffffff; int ml = -1;
            for (int i = lane; i < n; i += 64)
                if (better(sd[i], si[i], md, mi)) { md = sd[i]; mi = si[i]; ml = i; }
            #pragma unroll
            for (int off = 32; off > 0; off >>= 1) {
                float od = __shfl_down(md, off, 64);
                int   oi = __shfl_down(mi, off, 64);
                int   ol = __shfl_down(ml, off, 64);
                if (better(od, oi, md, mi)) { md = od; mi = oi; ml = ol; }
            }
            md = __shfl(md, 0, 64); mi = __shfl(mi, 0, 64); ml = __shfl(ml, 0, 64);
            kd[sel] = md; ki[sel] = mi;
            if (lane == 0 && ml >= 0) { sd[ml] = 3.4e38f; si[ml] = 0x7fffffff; }
        }
        __syncthreads();
    }

    if (tid == 0) {
        bool anyzero = false;
        float dist[KNN];
        #pragma unroll
        for (int j = 0; j < KNN; ++j) {
            dist[j] = sqrtf(fmaxf(kd[j], 0.f));
            if (dist[j] == 0.f) anyzero = true;
        }
        #pragma unroll
        for (int c = 0; c < NCLS; ++c) spr[c] = 0.f;
        #pragma unroll
        for (int j = 0; j < KNN; ++j) {
            int idxj = ki[j];
            if (idxj < 0 || idxj >= M_TRAIN) continue;   // sentinel guard
            float wgt = anyzero ? (dist[j] == 0.f ? 1.f : 0.f) : 1.f / dist[j];
            spr[labels[idxj]] += wgt;
        }
        float s = 0.f;
        #pragma unroll
        for (int c = 0; c < NCLS; ++c) s += spr[c];
        if (s == 0.f) s = 1.f;
        float inv = 1.f / s;
        float best = -1.f; int bc = 0;
        #pragma unroll
        for (int c = 0; c < NCLS; ++c) {
            float pv = spr[c] * inv;
            out[NQ + (size_t)q * NCLS + c] = pv;
            if (pv > best) { best = pv; bc = c; }
        }
        out[q] = (float)bc;
    }
}

// ---------------------------------------------------------------------------
extern "C" void kernel_launch(void* const* d_in, const int* in_sizes, int n_in,
                              void* d_out, int out_size, void* d_ws, size_t ws_size,
                              hipStream_t stream) {
    const float* x      = (const float*)d_in[0];
    const float* train  = (const float*)d_in[1];
    const int*   labels = (const int*)d_in[2];
    float* out = (float*)d_out;

    // Byte-exact ws layout, IDENTICAL footprint to the round-5 passing kernel
    // (26,116,096 B total):
    //   t2 401,408 | x2 8,192 | tau 8,192 | cnt 8,192 |
    //   region @425,984: dsub 25,690,112 (dead after knn_select)
    //     -> reused as tb 12,845,056 (one bf16 half) + buf_i 6,291,456
    char* base = (char*)d_ws;
    float*  t2   = (float*)(base);
    float*  x2   = (float*)(base + 401408);
    float*  tau  = (float*)(base + 409600);
    int*    cnt  = (int*)  (base + 417792);
    char*   region = base + 425984;
    __half* dsub = (__half*)region;                        // 25,690,112 B
    unsigned int* tb = (unsigned int*)region;              // 12,845,056 B (aliases dsub)
    int*    bi   = (int*)(region + 12845056);              //  6,291,456 B (aliases dsub)

    int nrows = M_TRAIN + NQ;
    knn_norms<<<(nrows * 64 + 255) / 256, 256, 0, stream>>>(train, x, t2, x2);
    knn_zero_cnt<<<(NQ + 255) / 256, 256, 0, stream>>>(cnt);

    dim3 gs(SCH, NQ / MQ);
    knn_sub_mfma<<<gs, 256, 0, stream>>>(x, train, t2, x2, dsub);

    knn_select<<<NQ, 256, 0, stream>>>(dsub, tau);

    // dsub dead; process the train set in two bf16 halves over its storage.
    for (int h = 0; h < 2; ++h) {
        int rowBase = h * TBH;
        knn_convert_bf16<<<(TBH * 32) / 256, 256, 0, stream>>>(train, tb, rowBase);
        knn_bf16_filter<<<FCH * (NQ / MQ), 256, 0, stream>>>(
            x, (const short*)tb, t2, x2, tau, rowBase, bi, cnt);
    }

    knn_final<<<NQ, 256, 0, stream>>>(x, train, t2, x2, bi, cnt, labels, out);
}

// Round 9
// 494.410 us; speedup vs baseline: 1.3440x; 1.3440x over previous
//
#include <hip/hip_runtime.h>
#include <hip/hip_fp16.h>
#include <math.h>

#define M_TRAIN 100000
#define NQ 2048
#define DIM 128
#define KNN 16
#define NCLS 10

// Subsample for tau: every 16th train point; padded to 6272 = 49 * 128.
#define S_STRIDE 16
#define S_CNT (M_TRAIN / S_STRIDE)     // 6250
#define S_PAD 6272
#define SCH 49
#define SPC 128
#define TT 64
#define MQ 128
#define QSTR 136                       // LDS row stride in shorts (128 + 8 pad)

// Filter: one block = 64 queries x 128 train rows, K=128 in one shot.
#define CAP 768
#define TBH 50176                      // rows per half (392 * 128)
#define NTR 128                        // train rows per block
#define NQT 64                         // queries per block
#define MARGIN 3.0f                    // proven in rounds 4-5/8

using bfrag = __attribute__((ext_vector_type(8))) short;
using cfrag = __attribute__((ext_vector_type(4))) float;

__device__ __forceinline__ bool better(float d1, int i1, float d2, int i2) {
    return (d1 < d2) || (d1 == d2 && i1 < i2);
}

__device__ __forceinline__ unsigned pack_bf16(float a, float b) {
    unsigned ua = __float_as_uint(a), ub = __float_as_uint(b);
    ua += 0x7fffu + ((ua >> 16) & 1u);   // RNE
    ub += 0x7fffu + ((ub >> 16) & 1u);
    return (ua >> 16) | (ub & 0xffff0000u);
}

__device__ __forceinline__ bfrag pack_bf16x8(const float* p) {
    union { unsigned u[4]; bfrag f; } r;
    r.u[0] = pack_bf16(p[0], p[1]);
    r.u[1] = pack_bf16(p[2], p[3]);
    r.u[2] = pack_bf16(p[4], p[5]);
    r.u[3] = pack_bf16(p[6], p[7]);
    return r.f;
}

// ---------------------------------------------------------------------------
// Kernel 0: squared norms, one wave per row.
__global__ void knn_norms(const float* __restrict__ train,
                          const float* __restrict__ x,
                          float* __restrict__ t2, float* __restrict__ x2) {
    int gw = (blockIdx.x * blockDim.x + threadIdx.x) >> 6;
    int lane = threadIdx.x & 63;
    if (gw >= M_TRAIN + NQ) return;
    const float* r = (gw < M_TRAIN) ? (train + (size_t)gw * DIM)
                                    : (x + (size_t)(gw - M_TRAIN) * DIM);
    float a = r[lane];
    float b = r[lane + 64];
    float s = a * a + b * b;
    #pragma unroll
    for (int off = 32; off > 0; off >>= 1)
        s += __shfl_down(s, off, 64);
    if (lane == 0) {
        if (gw < M_TRAIN) t2[gw] = s; else x2[gw - M_TRAIN] = s;
    }
}

__global__ void knn_zero_cnt(int* __restrict__ cnt) {
    int i = blockIdx.x * blockDim.x + threadIdx.x;
    if (i < NQ) cnt[i] = 0;
}

// ---------------------------------------------------------------------------
// Kernel 1: MFMA (bf16) approx-d2 over the stride-16 subsample -> fp16 matrix.
__global__ __launch_bounds__(256, 2)
void knn_sub_mfma(const float* __restrict__ x, const float* __restrict__ train,
                  const float* __restrict__ t2, const float* __restrict__ x2,
                  __half* __restrict__ dsub) {
    __shared__ short Q[MQ * QSTR];
    __shared__ short T[TT * QSTR];
    __shared__ float t2h[TT];
    int tid = threadIdx.x;
    int w = tid >> 6, lane = tid & 63;
    int rquad = lane >> 4, rcol = lane & 15;
    int qBase = blockIdx.y * MQ;
    int cBase = blockIdx.x * SPC;

    #pragma unroll
    for (int it = 0; it < 16; ++it) {
        int f = it * 256 + tid;
        int row = f >> 5, c4 = f & 31;
        float4 v = ((const float4*)x)[(size_t)(qBase + row) * (DIM / 4) + c4];
        uint2 p; p.x = pack_bf16(v.x, v.y); p.y = pack_bf16(v.z, v.w);
        *(uint2*)&Q[row * QSTR + c4 * 4] = p;
    }
    __syncthreads();

    float x2r[2][4];
    #pragma unroll
    for (int rt = 0; rt < 2; ++rt)
        #pragma unroll
        for (int reg = 0; reg < 4; ++reg)
            x2r[rt][reg] = x2[qBase + w * 32 + rt * 16 + rquad * 4 + reg];

    bfrag A[2][4];
    #pragma unroll
    for (int rt = 0; rt < 2; ++rt)
        #pragma unroll
        for (int ks = 0; ks < 4; ++ks) {
            int r = w * 32 + rt * 16 + rcol;
            A[rt][ks] = *(const bfrag*)&Q[r * QSTR + ks * 32 + rquad * 8];
        }

    const cfrag zero4 = {0.f, 0.f, 0.f, 0.f};
    for (int t = 0; t < 2; ++t) {
        __syncthreads();
        int sBase = cBase + t * TT;
        #pragma unroll
        for (int it = 0; it < 8; ++it) {
            int f = it * 256 + tid;
            int row = f >> 5, c4 = f & 31;
            int sj = sBase + row;
            bool ok = sj < S_CNT;
            float4 v = ok ? ((const float4*)train)[(size_t)sj * S_STRIDE * (DIM / 4) + c4]
                          : make_float4(0.f, 0.f, 0.f, 0.f);
            uint2 p; p.x = pack_bf16(v.x, v.y); p.y = pack_bf16(v.z, v.w);
            *(uint2*)&T[row * QSTR + c4 * 4] = p;
        }
        if (tid < TT) {
            int sj = sBase + tid;
            t2h[tid] = (sj < S_CNT) ? t2[(size_t)sj * S_STRIDE] : 1e30f;
        }
        __syncthreads();

        cfrag acc[2][4];
        #pragma unroll
        for (int ks = 0; ks < 4; ++ks) {
            bfrag B[4];
            #pragma unroll
            for (int ct = 0; ct < 4; ++ct) {
                int n = ct * 16 + rcol;
                B[ct] = *(const bfrag*)&T[n * QSTR + ks * 32 + rquad * 8];
            }
            #pragma unroll
            for (int rt = 0; rt < 2; ++rt)
                #pragma unroll
                for (int ct = 0; ct < 4; ++ct)
                    acc[rt][ct] = (ks == 0)
                        ? __builtin_amdgcn_mfma_f32_16x16x32_bf16(A[rt][0], B[ct], zero4, 0, 0, 0)
                        : __builtin_amdgcn_mfma_f32_16x16x32_bf16(A[rt][ks], B[ct], acc[rt][ct], 0, 0, 0);
        }

        float th[4];
        #pragma unroll
        for (int ct = 0; ct < 4; ++ct) th[ct] = t2h[ct * 16 + rcol];
        #pragma unroll
        for (int rt = 0; rt < 2; ++rt)
            #pragma unroll
            for (int ct = 0; ct < 4; ++ct)
                #pragma unroll
                for (int reg = 0; reg < 4; ++reg) {
                    float d2 = x2r[rt][reg] + th[ct] - 2.f * acc[rt][ct][reg];
                    int qrow = qBase + w * 32 + rt * 16 + rquad * 4 + reg;
                    int col = sBase + ct * 16 + rcol;
                    dsub[(size_t)qrow * S_PAD + col] = __float2half_rn(d2);
                }
    }
}

// ---------------------------------------------------------------------------
// Kernel 2: tau[q] = 16th-smallest value of dsub row q (values only).
__global__ __launch_bounds__(256)
void knn_select(const __half* __restrict__ dsub, float* __restrict__ tau) {
    __shared__ float wv[4];
    __shared__ int   wc[4];
    __shared__ float sv;
    __shared__ int   sc;
    int q = blockIdx.x, tid = threadIdx.x;
    int w = tid >> 6, lane = tid & 63;

    float bd[KNN];
    #pragma unroll
    for (int j = 0; j < KNN; ++j) bd[j] = 3.4e38f;
    for (int k = 0; k < 25; ++k) {
        int idx = k * 256 + tid;
        if (idx < S_PAD) {
            float v = __half2float(dsub[(size_t)q * S_PAD + idx]);
            if (v < bd[KNN - 1]) {
                bd[KNN - 1] = v;
                #pragma unroll
                for (int j = KNN - 1; j >= 1; --j)
                    if (bd[j] < bd[j - 1]) { float t = bd[j]; bd[j] = bd[j - 1]; bd[j - 1] = t; }
            }
        }
    }

    float last = 3.4e38f;
    for (int sel = 0; sel < KNN; ++sel) {
        float mv = bd[0]; int mj = 0;
        #pragma unroll
        for (int j = 1; j < KNN; ++j) if (bd[j] < mv) { mv = bd[j]; mj = j; }
        int mc = (tid << 4) | mj;
        #pragma unroll
        for (int off = 32; off > 0; off >>= 1) {
            float ov = __shfl_down(mv, off, 64);
            int   oc = __shfl_down(mc, off, 64);
            if (ov < mv) { mv = ov; mc = oc; }
        }
        if (lane == 0) { wv[w] = mv; wc[w] = mc; }
        __syncthreads();
        if (tid == 0) {
            float bv = wv[0]; int bc = wc[0];
            #pragma unroll
            for (int i = 1; i < 4; ++i) if (wv[i] < bv) { bv = wv[i]; bc = wc[i]; }
            sv = bv; sc = bc;
        }
        __syncthreads();
        last = sv;
        if (tid == (sc >> 4)) {
            int j0 = sc & 15;
            #pragma unroll
            for (int j = 0; j < KNN; ++j) if (j == j0) bd[j] = 3.4e38f;
        }
        __syncthreads();
    }
    if (tid == 0) tau[q] = last;
}

// ---------------------------------------------------------------------------
// Kernel 3: fp32 -> bf16 conversion of one train half (pad rows zero-filled).
// Runs AFTER knn_select: tb aliases the dead dsub region.
__global__ __launch_bounds__(256)
void knn_convert_bf16(const float* __restrict__ train,
                      unsigned int* __restrict__ tb, int rowBase) {
    int i = blockIdx.x * 256 + threadIdx.x;        // one thread per 4 floats
    int row = i >> 5, seg = i & 31;                // row in [0, TBH)
    int g = rowBase + row;
    float4 v = (g < M_TRAIN)
        ? ((const float4*)train)[(size_t)g * (DIM / 4) + seg]
        : make_float4(0.f, 0.f, 0.f, 0.f);
    uint2 p; p.x = pack_bf16(v.x, v.y); p.y = pack_bf16(v.z, v.w);
    ((uint2*)tb)[(size_t)row * 32 + seg] = p;
}

// ---------------------------------------------------------------------------
// Kernel 4: bf16 MFMA filter, one block = 64 queries x 128 train rows, K=128
// in one shot (no serial tile loop). Train tile (bf16 tb) staged to padded
// LDS once; A-frags packed in-kernel from fp32 x; one barrier; 32 MFMA/wave;
// compare+push epilogue. Inter-block overlap (49 blocks/CU queued) hides the
// staging latency.
__global__ __launch_bounds__(256, 3)
void knn_filter2(const float* __restrict__ x, const short* __restrict__ tbb,
                 const float* __restrict__ t2, const float* __restrict__ x2,
                 const float* __restrict__ tau, int pBase0,
                 int* __restrict__ buf_i, int* __restrict__ cnt) {
    __shared__ short T[NTR][QSTR];       // 128 x 136 shorts = 34816 B
    int tid = threadIdx.x;
    int w = tid >> 6, lane = tid & 63;
    int rquad = lane >> 4, rcol = lane & 15;
    // q-blocks contiguous within an N-tile -> train tile L2-resident.
    int bid = blockIdx.x;
    int nchunk = bid >> 5, qb = bid & 31;
    int qBase = qb * NQT;
    int tLoc = nchunk * NTR;             // local row within this half

    // Stage train tile: 128 rows x 256 B, 16 B/lane, 8 iters.
    #pragma unroll
    for (int it = 0; it < 8; ++it) {
        int s = it * 256 + tid;
        int row = s >> 4, c8 = s & 15;
        bfrag v = *(const bfrag*)&tbb[(size_t)(tLoc + row) * DIM + c8 * 8];
        *(bfrag*)&T[row][c8 * 8] = v;
    }

    // A-frags for this wave's 16 query rows: A[m=rcol][k=rquad*8+j].
    bfrag A[4];
    int qrow = qBase + w * 16 + rcol;
    #pragma unroll
    for (int ks = 0; ks < 4; ++ks)
        A[ks] = pack_bf16x8(&x[(size_t)qrow * DIM + ks * 32 + rquad * 8]);

    float RC[4];
    #pragma unroll
    for (int reg = 0; reg < 4; ++reg) {
        int q = qBase + w * 16 + rquad * 4 + reg;
        RC[reg] = 0.5f * (x2[q] - tau[q] - MARGIN);
    }
    float th[8];
    #pragma unroll
    for (int ct = 0; ct < 8; ++ct) {
        int g = pBase0 + tLoc + ct * 16 + rcol;   // < 100352 = t2 allocation
        th[ct] = 0.5f * t2[g];                    // pad rows: poison, idx-guarded
    }
    __syncthreads();

    const cfrag zero4 = {0.f, 0.f, 0.f, 0.f};
    cfrag acc[8];
    #pragma unroll
    for (int ks = 0; ks < 4; ++ks)
        #pragma unroll
        for (int ct = 0; ct < 8; ++ct) {
            bfrag B = *(const bfrag*)&T[ct * 16 + rcol][ks * 32 + rquad * 8];
            acc[ct] = (ks == 0)
                ? __builtin_amdgcn_mfma_f32_16x16x32_bf16(A[0], B, zero4, 0, 0, 0)
                : __builtin_amdgcn_mfma_f32_16x16x32_bf16(A[ks], B, acc[ct], 0, 0, 0);
        }

    #pragma unroll
    for (int ct = 0; ct < 8; ++ct)
        #pragma unroll
        for (int reg = 0; reg < 4; ++reg) {
            float s = acc[ct][reg];
            int idx = pBase0 + tLoc + ct * 16 + rcol;
            if (s >= RC[reg] + th[ct] && idx < M_TRAIN) {
                int q = qBase + w * 16 + rquad * 4 + reg;
                int slot = atomicAdd(&cnt[q], 1);
                if (slot < CAP)
                    buf_i[(size_t)q * CAP + slot] = idx;
            }
        }
}

// ---------------------------------------------------------------------------
// Kernel 5: exact fp32 re-rank + weighted vote. 256 thr: 16 lanes/candidate.
__global__ __launch_bounds__(256)
void knn_final(const float* __restrict__ x,
               const float* __restrict__ train,
               const float* __restrict__ t2v,
               const float* __restrict__ x2v,
               const int* __restrict__ buf_i,
               const int* __restrict__ cnt,
               const int* __restrict__ labels,
               float* __restrict__ out) {
    __shared__ float sd[CAP];
    __shared__ int   si[CAP];
    __shared__ float spr[NCLS];
    int q = blockIdx.x;
    int tid = threadIdx.x;
    int w = tid >> 6, lane = tid & 63;
    int grp = lane >> 4;
    int sub = lane & 15;
    int n = cnt[q]; if (n > CAP) n = CAP;

    const float4* xq = (const float4*)&x[(size_t)q * DIM + sub * 8];
    float4 qa = xq[0], qb = xq[1];
    float x2l = x2v[q];

    for (int base = 0; base < n; base += 16) {
        int i = base + w * 4 + grp;
        if (i < n) {
            int idx = buf_i[(size_t)q * CAP + i];
            const float4* tr = (const float4*)&train[(size_t)idx * DIM + sub * 8];
            float4 ta = tr[0], tb4 = tr[1];
            float s = qa.x * ta.x + qa.y * ta.y + qa.z * ta.z + qa.w * ta.w
                    + qb.x * tb4.x + qb.y * tb4.y + qb.z * tb4.z + qb.w * tb4.w;
            s += __shfl_xor(s, 1, 64);
            s += __shfl_xor(s, 2, 64);
            s += __shfl_xor(s, 4, 64);
            s += __shfl_xor(s, 8, 64);
            if (sub == 0) { sd[i] = x2l + t2v[idx] - 2.f * s; si[i] = idx; }
        }
    }
    __syncthreads();

    float kd[KNN];
    int   ki[KNN];
    for (int sel = 0; sel < KNN; ++sel) {
        if (w == 0) {
            float md = 3.4e38f; int mi = 0x7fffffff; int ml = -1;
            for (int i = lane; i < n; i += 64)
                if (better(sd[i], si[i], md, mi)) { md = sd[i]; mi = si[i]; ml = i; }
            #pragma unroll
            for (int off = 32; off > 0; off >>= 1) {
                float od = __shfl_down(md, off, 64);
                int   oi = __shfl_down(mi, off, 64);
                int   ol = __shfl_down(ml, off, 64);
                if (better(od, oi, md, mi)) { md = od; mi = oi; ml = ol; }
            }
            md = __shfl(md, 0, 64); mi = __shfl(mi, 0, 64); ml = __shfl(ml, 0, 64);
            kd[sel] = md; ki[sel] = mi;
            if (lane == 0 && ml >= 0) { sd[ml] = 3.4e38f; si[ml] = 0x7fffffff; }
        }
        __syncthreads();
    }

    if (tid == 0) {
        bool anyzero = false;
        float dist[KNN];
        #pragma unroll
        for (int j = 0; j < KNN; ++j) {
            dist[j] = sqrtf(fmaxf(kd[j], 0.f));
            if (dist[j] == 0.f) anyzero = true;
        }
        #pragma unroll
        for (int c = 0; c < NCLS; ++c) spr[c] = 0.f;
        #pragma unroll
        for (int j = 0; j < KNN; ++j) {
            int idxj = ki[j];
            if (idxj < 0 || idxj >= M_TRAIN) continue;   // sentinel guard
            float wgt = anyzero ? (dist[j] == 0.f ? 1.f : 0.f) : 1.f / dist[j];
            spr[labels[idxj]] += wgt;
        }
        float s = 0.f;
        #pragma unroll
        for (int c = 0; c < NCLS; ++c) s += spr[c];
        if (s == 0.f) s = 1.f;
        float inv = 1.f / s;
        float best = -1.f; int bc = 0;
        #pragma unroll
        for (int c = 0; c < NCLS; ++c) {
            float pv = spr[c] * inv;
            out[NQ + (size_t)q * NCLS + c] = pv;
            if (pv > best) { best = pv; bc = c; }
        }
        out[q] = (float)bc;
    }
}

// ---------------------------------------------------------------------------
extern "C" void kernel_launch(void* const* d_in, const int* in_sizes, int n_in,
                              void* d_out, int out_size, void* d_ws, size_t ws_size,
                              hipStream_t stream) {
    const float* x      = (const float*)d_in[0];
    const float* train  = (const float*)d_in[1];
    const int*   labels = (const int*)d_in[2];
    float* out = (float*)d_out;

    // Byte-exact ws layout, IDENTICAL footprint to rounds 5/8 (26,116,096 B):
    //   t2 401,408 | x2 8,192 | tau 8,192 | cnt 8,192 |
    //   region @425,984: dsub 25,690,112 (dead after knn_select)
    //     -> reused as tb 12,845,056 (one bf16 half) + buf_i 6,291,456
    char* base = (char*)d_ws;
    float*  t2   = (float*)(base);
    float*  x2   = (float*)(base + 401408);
    float*  tau  = (float*)(base + 409600);
    int*    cnt  = (int*)  (base + 417792);
    char*   region = base + 425984;
    __half* dsub = (__half*)region;                        // 25,690,112 B
    unsigned int* tb = (unsigned int*)region;              // 12,845,056 B (aliases dsub)
    int*    bi   = (int*)(region + 12845056);              //  6,291,456 B (aliases dsub)

    int nrows = M_TRAIN + NQ;
    knn_norms<<<(nrows * 64 + 255) / 256, 256, 0, stream>>>(train, x, t2, x2);
    knn_zero_cnt<<<(NQ + 255) / 256, 256, 0, stream>>>(cnt);

    dim3 gs(SCH, NQ / MQ);
    knn_sub_mfma<<<gs, 256, 0, stream>>>(x, train, t2, x2, dsub);

    knn_select<<<NQ, 256, 0, stream>>>(dsub, tau);

    // dsub dead; process the train set in two bf16 halves over its storage.
    for (int h = 0; h < 2; ++h) {
        int rowBase = h * TBH;
        knn_convert_bf16<<<(TBH * 32) / 256, 256, 0, stream>>>(train, tb, rowBase);
        knn_filter2<<<(TBH / NTR) * (NQ / NQT), 256, 0, stream>>>(
            x, (const short*)tb, t2, x2, tau, rowBase, bi, cnt);
    }

    knn_final<<<NQ, 256, 0, stream>>>(x, train, t2, x2, bi, cnt, labels, out);
}